// Round 1
// baseline (59.368 us; speedup 1.0000x reference)
//
#include <hip/hip_runtime.h>

// -------------------------------------------------------------------------
// PhonemeLengthRegulator:
//   per-syllable masked softmax over <=16 phoneme logits, scaled by beat_syb,
//   scattered at exclusive-cumsum(counts) offsets into beat[B, T].
//   Offsets are non-overlapping per batch -> plain writes, no atomics.
// -------------------------------------------------------------------------

// Kernel 1: per-batch exclusive cumsum of valid syllable counts.
// One block per batch. 256 threads, ITEMS = ceil(S/256) items each.
__global__ void plr_scan_offsets(const int* __restrict__ syllable_num,
                                 const int* __restrict__ syllable_lengths,
                                 int* __restrict__ offsets,
                                 int S) {
    const int b = blockIdx.x;
    const int len = syllable_lengths[b];
    const int* n = syllable_num + (size_t)b * S;
    int* off = offsets + (size_t)b * S;

    __shared__ int partial[256];
    const int t = threadIdx.x;
    const int items = (S + 255) / 256;
    const int start = t * items;

    // local sum of this thread's chunk
    int local = 0;
    for (int k = 0; k < items; ++k) {
        int j = start + k;
        if (j < S) local += (j < len) ? n[j] : 0;
    }
    partial[t] = local;
    __syncthreads();

    // Hillis-Steele inclusive scan over the 256 partials
    for (int d = 1; d < 256; d <<= 1) {
        int u = (t >= d) ? partial[t - d] : 0;
        __syncthreads();
        partial[t] += u;
        __syncthreads();
    }

    // exclusive prefix for this thread's chunk, then sequential walk
    int running = partial[t] - local;
    for (int k = 0; k < items; ++k) {
        int j = start + k;
        if (j < S) {
            off[j] = running;
            running += (j < len) ? n[j] : 0;
        }
    }
}

// Kernel 2: masked softmax + scatter. 16 lanes cooperate on one syllable.
// P is fixed at 16 for this problem (phonemes per syllable).
__global__ void plr_scatter(const int*   __restrict__ syllable_num,
                            const int*   __restrict__ syllable_lengths,
                            const float* __restrict__ beat_syb,
                            const float* __restrict__ ds_alf,
                            const int*   __restrict__ offsets,
                            float*       __restrict__ beat,
                            int S, int T) {
    const int tid  = blockIdx.x * blockDim.x + threadIdx.x;
    const int sid  = tid >> 4;        // syllable index across all batches
    const int lane = tid & 15;        // phoneme slot within syllable
    const int b    = sid / S;
    const int j    = sid - b * S;

    const float x = ds_alf[((size_t)sid << 4) + lane];   // coalesced
    const int   n = syllable_num[sid];
    const bool  ph_valid = lane < n;
    const bool  valid    = ph_valid && (j < syllable_lengths[b]);

    // max over the 16-lane group (invalid lanes contribute -inf-ish)
    float m = ph_valid ? x : -1e30f;
    #pragma unroll
    for (int d = 8; d >= 1; d >>= 1)
        m = fmaxf(m, __shfl_xor(m, d, 16));

    // exp & sum; invalid lanes contribute exactly 0 (== reference's -1e9 mask
    // followed by multiplying with the validity mask)
    float e = ph_valid ? expf(x - m) : 0.0f;
    float s = e;
    #pragma unroll
    for (int d = 8; d >= 1; d >>= 1)
        s += __shfl_xor(s, d, 16);

    const float val = beat_syb[sid] * (e / s);

    if (valid) {
        beat[(size_t)b * T + offsets[sid] + lane] = val;
    }
}

// Kernel 3: second tuple output — label_xml_lengths, stored as float32 in the
// flat output buffer right after beat.
__global__ void plr_write_lengths(const int* __restrict__ lens,
                                  float* __restrict__ out, int B) {
    const int i = blockIdx.x * blockDim.x + threadIdx.x;
    if (i < B) out[i] = (float)lens[i];
}

extern "C" void kernel_launch(void* const* d_in, const int* in_sizes, int n_in,
                              void* d_out, int out_size, void* d_ws, size_t ws_size,
                              hipStream_t stream) {
    // inputs (setup_inputs order):
    // 0 syllable (B,S,D) f32 — UNUSED by reference
    // 1 syllable_num (B,S) i32
    // 2 syllable_lengths (B,) i32
    // 3 beat_syb (B,S) f32
    // 4 ds_alf (B,S,P) f32
    // 5 label_xml (B,T) i32 — zeros, unused
    // 6 label_xml_lengths (B,) i32
    const int*   syllable_num     = (const int*)  d_in[1];
    const int*   syllable_lengths = (const int*)  d_in[2];
    const float* beat_syb         = (const float*)d_in[3];
    const float* ds_alf           = (const float*)d_in[4];
    const int*   label_lengths    = (const int*)  d_in[6];

    const int B = in_sizes[2];
    const int S = in_sizes[1] / B;
    const int T = in_sizes[5] / B;

    float* beat = (float*)d_out;
    int*   offsets = (int*)d_ws;   // B*S ints = 2 MB

    // beat must be zero everywhere we don't write (harness poisons d_out once
    // with 0xAA and does not re-poison between timed replays)
    hipMemsetAsync(d_out, 0, (size_t)B * T * sizeof(float), stream);

    plr_scan_offsets<<<B, 256, 0, stream>>>(syllable_num, syllable_lengths,
                                            offsets, S);

    const long long total = (long long)B * S * 16;
    plr_scatter<<<(int)(total / 256), 256, 0, stream>>>(
        syllable_num, syllable_lengths, beat_syb, ds_alf, offsets, beat, S, T);

    plr_write_lengths<<<(B + 255) / 256, 256, 0, stream>>>(
        label_lengths, beat + (size_t)B * T, B);
}

// Round 2
// 42.735 us; speedup vs baseline: 1.3892x; 1.3892x over previous
//
#include <hip/hip_runtime.h>

// -------------------------------------------------------------------------
// PhonemeLengthRegulator:
//   per-syllable masked softmax over <=16 phoneme logits, scaled by beat_syb,
//   scattered at exclusive-cumsum(counts) offsets into beat[B, T].
//   Valid writes densely tile beat[b, 0:label_len[b]]; only the tail
//   [label_len[b], T) needs zeroing. Offsets non-overlapping -> no atomics.
// -------------------------------------------------------------------------

// Kernel 1: per-batch exclusive cumsum of valid syllable counts.
// One block per batch, 1024 threads, 8 items/thread (S <= 8192).
// Wave-level shfl scan + one LDS cross-wave scan; int4 vectorized I/O.
__global__ __launch_bounds__(1024) void plr_scan(
        const int* __restrict__ syllable_num,
        const int* __restrict__ syllable_lengths,
        int* __restrict__ offsets, int S) {
    const int b   = blockIdx.x;
    const int len = syllable_lengths[b];
    const int* n  = syllable_num + (size_t)b * S;
    int* off      = offsets + (size_t)b * S;

    const int t    = threadIdx.x;
    const int lane = t & 63;
    const int wid  = t >> 6;
    const int base = t * 8;

    // load 8 counts (vector fast path), mask invalid syllables
    int c[8];
    if (base + 8 <= S) {
        int4 a = *(const int4*)(n + base);
        int4 d = *(const int4*)(n + base + 4);
        c[0]=a.x; c[1]=a.y; c[2]=a.z; c[3]=a.w;
        c[4]=d.x; c[5]=d.y; c[6]=d.z; c[7]=d.w;
    } else {
        #pragma unroll
        for (int k = 0; k < 8; ++k) c[k] = (base + k < S) ? n[base + k] : 0;
    }
    #pragma unroll
    for (int k = 0; k < 8; ++k) if (base + k >= len) c[k] = 0;

    // thread-local inclusive prefix
    int inc[8];
    int run = 0;
    #pragma unroll
    for (int k = 0; k < 8; ++k) { run += c[k]; inc[k] = run; }
    const int localsum = run;

    // wave-level inclusive scan of per-thread sums
    int ws = localsum;
    #pragma unroll
    for (int d = 1; d < 64; d <<= 1) {
        int u = __shfl_up(ws, d, 64);
        if (lane >= d) ws += u;
    }

    // cross-wave scan (up to 16 waves)
    __shared__ int wsum[16];
    if (lane == 63) wsum[wid] = ws;
    __syncthreads();
    const int nw = blockDim.x >> 6;
    if (wid == 0) {
        int v = (lane < nw) ? wsum[lane] : 0;
        #pragma unroll
        for (int d = 1; d < 16; d <<= 1) {
            int u = __shfl_up(v, d, 64);
            if (lane >= d) v += u;
        }
        if (lane < nw) wsum[lane] = v;   // inclusive wave totals
    }
    __syncthreads();

    const int wavebase = (wid > 0) ? wsum[wid - 1] : 0;
    const int tbase    = wavebase + (ws - localsum);   // exclusive thread base

    int o[8];
    #pragma unroll
    for (int k = 0; k < 8; ++k) o[k] = tbase + inc[k] - c[k];

    if (base + 8 <= S) {
        *(int4*)(off + base)     = make_int4(o[0], o[1], o[2], o[3]);
        *(int4*)(off + base + 4) = make_int4(o[4], o[5], o[6], o[7]);
    } else {
        #pragma unroll
        for (int k = 0; k < 8; ++k) if (base + k < S) off[base + k] = o[k];
    }
}

// Kernel 2: zero only the tail beat[b, len_b:T] (float4), and emit the
// second tuple output (label_xml_lengths as float). Disjoint from scatter's
// write range [0, len_b) -> no ordering requirement between the two.
__global__ void plr_zero_tail(const int* __restrict__ lens,
                              float* __restrict__ beat,
                              float* __restrict__ len_out,
                              int T, int B) {
    const int tid = blockIdx.x * blockDim.x + threadIdx.x;
    if (tid < B) len_out[tid] = (float)lens[tid];

    const int per_batch = T >> 2;                // float4 slots per batch row
    const int b   = tid / per_batch;
    const int q   = tid - b * per_batch;
    const int pos = q << 2;
    const int len = lens[b];
    if (pos + 4 <= len) return;                  // fully covered by scatter
    float* row = beat + (size_t)b * T;
    if (pos >= len) {
        *(float4*)(row + pos) = make_float4(0.f, 0.f, 0.f, 0.f);
    } else {
        #pragma unroll
        for (int k = 0; k < 4; ++k)
            if (pos + k >= len) row[pos + k] = 0.f;
    }
}

// Kernel 3: masked softmax + scatter. 16 lanes cooperate on one syllable.
__global__ void plr_scatter(const int*   __restrict__ syllable_num,
                            const int*   __restrict__ syllable_lengths,
                            const float* __restrict__ beat_syb,
                            const float* __restrict__ ds_alf,
                            const int*   __restrict__ offsets,
                            float*       __restrict__ beat,
                            int S, int T) {
    const int tid  = blockIdx.x * blockDim.x + threadIdx.x;
    const int sid  = tid >> 4;        // syllable index across all batches
    const int lane = tid & 15;        // phoneme slot within syllable
    const int b    = sid / S;
    const int j    = sid - b * S;

    const float x = ds_alf[((size_t)sid << 4) + lane];   // coalesced
    const int   n = syllable_num[sid];
    const bool  ph_valid = lane < n;
    const bool  valid    = ph_valid && (j < syllable_lengths[b]);

    float m = ph_valid ? x : -1e30f;
    #pragma unroll
    for (int d = 8; d >= 1; d >>= 1)
        m = fmaxf(m, __shfl_xor(m, d, 16));

    float e = ph_valid ? __expf(x - m) : 0.0f;
    float s = e;
    #pragma unroll
    for (int d = 8; d >= 1; d >>= 1)
        s += __shfl_xor(s, d, 16);

    const float val = beat_syb[sid] * (e / s);

    if (valid) {
        beat[(size_t)b * T + offsets[sid] + lane] = val;
    }
}

extern "C" void kernel_launch(void* const* d_in, const int* in_sizes, int n_in,
                              void* d_out, int out_size, void* d_ws, size_t ws_size,
                              hipStream_t stream) {
    // inputs (setup_inputs order):
    // 0 syllable (B,S,D) f32 — UNUSED by reference
    // 1 syllable_num (B,S) i32
    // 2 syllable_lengths (B,) i32
    // 3 beat_syb (B,S) f32
    // 4 ds_alf (B,S,P) f32
    // 5 label_xml (B,T) i32 — zeros, unused
    // 6 label_xml_lengths (B,) i32
    const int*   syllable_num     = (const int*)  d_in[1];
    const int*   syllable_lengths = (const int*)  d_in[2];
    const float* beat_syb         = (const float*)d_in[3];
    const float* ds_alf           = (const float*)d_in[4];
    const int*   label_lengths    = (const int*)  d_in[6];

    const int B = in_sizes[2];
    const int S = in_sizes[1] / B;
    const int T = in_sizes[5] / B;

    float* beat    = (float*)d_out;
    int*   offsets = (int*)d_ws;   // B*S ints = 2 MB

    plr_scan<<<B, 1024, 0, stream>>>(syllable_num, syllable_lengths,
                                     offsets, S);

    const long long tail_threads = (long long)B * (T >> 2);
    plr_zero_tail<<<(int)((tail_threads + 255) / 256), 256, 0, stream>>>(
        label_lengths, beat, beat + (size_t)B * T, T, B);

    const long long total = (long long)B * S * 16;
    plr_scatter<<<(int)(total / 256), 256, 0, stream>>>(
        syllable_num, syllable_lengths, beat_syb, ds_alf, offsets, beat, S, T);
}

// Round 3
// 32.923 us; speedup vs baseline: 1.8032x; 1.2980x over previous
//
#include <hip/hip_runtime.h>

// -------------------------------------------------------------------------
// PhonemeLengthRegulator:
//   per-syllable masked softmax over <=16 phoneme logits, scaled by beat_syb,
//   scattered at exclusive-cumsum(counts) offsets into beat[B, T].
//   Valid writes densely tile beat[b, 0:label_len[b]]; only the tail
//   [label_len[b], T) needs zeroing. Offsets non-overlapping -> no atomics.
// -------------------------------------------------------------------------

// Kernel 1: per-batch exclusive cumsum of valid syllable counts.
// One block per batch, 1024 threads, 8 items/thread (S <= 8192).
__global__ __launch_bounds__(1024) void plr_scan(
        const int* __restrict__ syllable_num,
        const int* __restrict__ syllable_lengths,
        int* __restrict__ offsets, int S) {
    const int b   = blockIdx.x;
    const int len = syllable_lengths[b];
    const int* n  = syllable_num + (size_t)b * S;
    int* off      = offsets + (size_t)b * S;

    const int t    = threadIdx.x;
    const int lane = t & 63;
    const int wid  = t >> 6;
    const int base = t * 8;

    int c[8];
    if (base + 8 <= S) {
        int4 a = *(const int4*)(n + base);
        int4 d = *(const int4*)(n + base + 4);
        c[0]=a.x; c[1]=a.y; c[2]=a.z; c[3]=a.w;
        c[4]=d.x; c[5]=d.y; c[6]=d.z; c[7]=d.w;
    } else {
        #pragma unroll
        for (int k = 0; k < 8; ++k) c[k] = (base + k < S) ? n[base + k] : 0;
    }
    #pragma unroll
    for (int k = 0; k < 8; ++k) if (base + k >= len) c[k] = 0;

    int inc[8];
    int run = 0;
    #pragma unroll
    for (int k = 0; k < 8; ++k) { run += c[k]; inc[k] = run; }
    const int localsum = run;

    int ws = localsum;
    #pragma unroll
    for (int d = 1; d < 64; d <<= 1) {
        int u = __shfl_up(ws, d, 64);
        if (lane >= d) ws += u;
    }

    __shared__ int wsum[16];
    if (lane == 63) wsum[wid] = ws;
    __syncthreads();
    const int nw = blockDim.x >> 6;
    if (wid == 0) {
        int v = (lane < nw) ? wsum[lane] : 0;
        #pragma unroll
        for (int d = 1; d < 16; d <<= 1) {
            int u = __shfl_up(v, d, 64);
            if (lane >= d) v += u;
        }
        if (lane < nw) wsum[lane] = v;
    }
    __syncthreads();

    const int wavebase = (wid > 0) ? wsum[wid - 1] : 0;
    const int tbase    = wavebase + (ws - localsum);

    int o[8];
    #pragma unroll
    for (int k = 0; k < 8; ++k) o[k] = tbase + inc[k] - c[k];

    if (base + 8 <= S) {
        *(int4*)(off + base)     = make_int4(o[0], o[1], o[2], o[3]);
        *(int4*)(off + base + 4) = make_int4(o[4], o[5], o[6], o[7]);
    } else {
        #pragma unroll
        for (int k = 0; k < 8; ++k) if (base + k < S) off[base + k] = o[k];
    }
}

// Kernel 2 (fused): scatter (one THREAD per syllable, softmax in registers)
// + zero-tail + lengths output. grid = (scatter_chunks + tail_chunks, B).
__global__ __launch_bounds__(256) void plr_scatter_tail(
        const int*   __restrict__ syllable_num,
        const int*   __restrict__ syllable_lengths,
        const float* __restrict__ beat_syb,
        const float* __restrict__ ds_alf,
        const int*   __restrict__ offsets,
        const int*   __restrict__ lens,
        float*       __restrict__ beat,
        float*       __restrict__ len_out,
        int S, int T, int scatter_chunks) {
    const int b = blockIdx.y;

    if ((int)blockIdx.x < scatter_chunks) {
        // ---- scatter: one thread per syllable ----
        const int j = blockIdx.x * blockDim.x + threadIdx.x;
        if (j >= S) return;
        const size_t sid = (size_t)b * S + j;

        const float4* src = (const float4*)(ds_alf + (sid << 4));
        float4 v0 = src[0], v1 = src[1], v2 = src[2], v3 = src[3];
        float x[16] = { v0.x, v0.y, v0.z, v0.w,
                        v1.x, v1.y, v1.z, v1.w,
                        v2.x, v2.y, v2.z, v2.w,
                        v3.x, v3.y, v3.z, v3.w };

        const int n = syllable_num[sid];   // 1..16
        #pragma unroll
        for (int k = 0; k < 16; ++k)
            if (k >= n) x[k] = -INFINITY;  // exp underflows to exactly 0

        // max over valid (n >= 1 guaranteed)
        float m = x[0];
        #pragma unroll
        for (int k = 1; k < 16; ++k) m = fmaxf(m, x[k]);

        float e[16];
        float s = 0.0f;
        #pragma unroll
        for (int k = 0; k < 16; ++k) { e[k] = __expf(x[k] - m); s += e[k]; }

        const float scale = beat_syb[sid] / s;

        if (j < syllable_lengths[b]) {
            float* dst = beat + (size_t)b * T + offsets[sid];
            #pragma unroll
            for (int k = 0; k < 16; ++k)
                if (k < n) dst[k] = e[k] * scale;   // static index, predicated
        }
    } else {
        // ---- zero tail beat[b, len:T] + lengths output ----
        const int q   = (blockIdx.x - scatter_chunks) * blockDim.x + threadIdx.x;
        const int pos = q << 2;
        if (pos >= T) return;
        const int len = lens[b];
        if ((int)blockIdx.x == scatter_chunks && threadIdx.x == 0)
            len_out[b] = (float)len;
        if (pos + 4 <= len) return;                 // covered by scatter
        float* row = beat + (size_t)b * T + pos;
        if (pos >= len) {
            *(float4*)row = make_float4(0.f, 0.f, 0.f, 0.f);
        } else {
            #pragma unroll
            for (int k = 0; k < 4; ++k)
                if (pos + k >= len) row[k] = 0.f;
        }
    }
}

extern "C" void kernel_launch(void* const* d_in, const int* in_sizes, int n_in,
                              void* d_out, int out_size, void* d_ws, size_t ws_size,
                              hipStream_t stream) {
    // inputs (setup_inputs order):
    // 0 syllable (B,S,D) f32 — UNUSED by reference
    // 1 syllable_num (B,S) i32
    // 2 syllable_lengths (B,) i32
    // 3 beat_syb (B,S) f32
    // 4 ds_alf (B,S,P) f32
    // 5 label_xml (B,T) i32 — zeros, unused
    // 6 label_xml_lengths (B,) i32
    const int*   syllable_num     = (const int*)  d_in[1];
    const int*   syllable_lengths = (const int*)  d_in[2];
    const float* beat_syb         = (const float*)d_in[3];
    const float* ds_alf           = (const float*)d_in[4];
    const int*   label_lengths    = (const int*)  d_in[6];

    const int B = in_sizes[2];
    const int S = in_sizes[1] / B;
    const int T = in_sizes[5] / B;

    float* beat    = (float*)d_out;
    int*   offsets = (int*)d_ws;   // B*S ints = 2 MB

    plr_scan<<<B, 1024, 0, stream>>>(syllable_num, syllable_lengths,
                                     offsets, S);

    const int scatter_chunks = (S + 255) / 256;          // 32
    const int tail_chunks    = ((T >> 2) + 255) / 256;   // 128
    dim3 grid(scatter_chunks + tail_chunks, B);
    plr_scatter_tail<<<grid, 256, 0, stream>>>(
        syllable_num, syllable_lengths, beat_syb, ds_alf, offsets,
        label_lengths, beat, beat + (size_t)B * T, S, T, scatter_chunks);
}

// Round 4
// 21.879 us; speedup vs baseline: 2.7135x; 1.5048x over previous
//
#include <hip/hip_runtime.h>

// -------------------------------------------------------------------------
// PhonemeLengthRegulator, single fused kernel.
//   per-syllable masked softmax over <=16 phoneme logits, scaled by beat_syb,
//   scattered at exclusive-cumsum(counts) offsets into beat[B, T].
//   Key facts exploited:
//    - offsets are an exclusive cumsum -> each 256-syllable chunk writes ONE
//      contiguous span of beat[b,:]. Stage values in LDS at local offsets,
//      then write the span out fully coalesced as float4.
//    - chunk base offset = reduce(counts[0:chunk_start)) computed in-block
//      (L2-resident redundant read) -> no separate scan kernel, no workspace.
//    - valid writes densely tile beat[b, 0:label_len[b]); only the tail
//      [label_len[b], T) needs zeroing (harness poisons d_out with 0xAA).
// -------------------------------------------------------------------------

__global__ __launch_bounds__(256) void plr_fused(
        const int*   __restrict__ syllable_num,
        const int*   __restrict__ syllable_lengths,
        const float* __restrict__ beat_syb,
        const float* __restrict__ ds_alf,
        const int*   __restrict__ lens,
        float*       __restrict__ beat,
        float*       __restrict__ len_out,
        int S, int T, int scatter_chunks) {
    const int b = blockIdx.y;
    const int t = threadIdx.x;

    if ((int)blockIdx.x < scatter_chunks) {
        // ================= scatter chunk: 256 syllables =================
        const int chunk = blockIdx.x;
        const int j     = chunk * 256 + t;           // syllable index
        const int slen  = syllable_lengths[b];
        const int* nrow = syllable_num + (size_t)b * S;
        const int lane  = t & 63, wid = t >> 6;

        // ---- base offset: sum counts[0 : chunk*256) masked by slen ----
        int pref = 0;
        const int nv4 = (chunk * 256) >> 2;          // whole int4s (chunk*256 <= S)
        const int4* nrow4 = (const int4*)nrow;
        for (int i = t; i < nv4; i += 256) {
            int4 v = nrow4[i];
            const int base = i * 4;
            pref += ((base + 0) < slen ? v.x : 0)
                  + ((base + 1) < slen ? v.y : 0)
                  + ((base + 2) < slen ? v.z : 0)
                  + ((base + 3) < slen ? v.w : 0);
        }
        #pragma unroll
        for (int d = 32; d >= 1; d >>= 1) pref += __shfl_xor(pref, d, 64);

        __shared__ int wred[4];
        __shared__ int wsum[4];
        if (lane == 0) wred[wid] = pref;

        // ---- this chunk's counts + block scan ----
        const bool in_s = (j < S);
        const int  n    = in_s ? nrow[j] : 0;              // 1..16
        const int  cnt  = (in_s && j < slen) ? n : 0;

        int sc = cnt;                                       // wave inclusive scan
        #pragma unroll
        for (int d = 1; d < 64; d <<= 1) {
            int u = __shfl_up(sc, d, 64);
            if (lane >= d) sc += u;
        }
        if (lane == 63) wsum[wid] = sc;
        __syncthreads();

        const int block_base = wred[0] + wred[1] + wred[2] + wred[3];
        int wbase = 0;
        #pragma unroll
        for (int w = 0; w < 4; ++w) if (w < wid) wbase += wsum[w];
        const int local_off = wbase + sc - cnt;             // exclusive scan
        const int span      = wsum[0] + wsum[1] + wsum[2] + wsum[3];

        // ---- masked softmax into LDS stage ----
        __shared__ float stage[4096];                       // 256*16 floats, 16 KB
        if (cnt > 0) {
            const size_t sid = (size_t)b * S + j;
            const float4* src = (const float4*)(ds_alf + (sid << 4));
            float4 v0 = src[0], v1 = src[1], v2 = src[2], v3 = src[3];
            float x[16] = { v0.x, v0.y, v0.z, v0.w,
                            v1.x, v1.y, v1.z, v1.w,
                            v2.x, v2.y, v2.z, v2.w,
                            v3.x, v3.y, v3.z, v3.w };
            #pragma unroll
            for (int k = 0; k < 16; ++k)
                if (k >= n) x[k] = -INFINITY;               // exp -> exactly 0

            float m = x[0];
            #pragma unroll
            for (int k = 1; k < 16; ++k) m = fmaxf(m, x[k]);

            float e[16];
            float s = 0.0f;
            #pragma unroll
            for (int k = 0; k < 16; ++k) { e[k] = __expf(x[k] - m); s += e[k]; }

            const float scale = beat_syb[sid] / s;
            #pragma unroll
            for (int k = 0; k < 16; ++k)
                if (k < n) stage[local_off + k] = e[k] * scale;
        }
        __syncthreads();

        // ---- coalesced span write: beat[b, block_base : block_base+span) ----
        if (span == 0) return;
        float* row = beat + (size_t)b * T;
        const int gbeg = block_base;
        const int gend = block_base + span;
        const int a0   = (gbeg + 3) & ~3;                   // first aligned f4
        const int a1   = gend & ~3;                         // end of aligned body

        // scalar head (<=3 elems)
        const int hend = (a0 < gend) ? a0 : gend;
        if (t < hend - gbeg) row[gbeg + t] = stage[t];
        // float4 body
        for (int p = a0 + 4 * t; p + 4 <= gend; p += 4 * 256) {
            const int l = p - gbeg;
            *(float4*)(row + p) =
                make_float4(stage[l], stage[l+1], stage[l+2], stage[l+3]);
        }
        // scalar tail (<=3 elems)
        const int tbeg = (a1 > a0) ? a1 : a0;
        if (tbeg < gend && t < gend - tbeg)
            row[tbeg + t] = stage[tbeg - gbeg + t];
    } else {
        // ============== zero tail beat[b, len:T) + lengths out ==============
        const int q   = (blockIdx.x - scatter_chunks) * 256 + t;
        const int pos = q << 2;
        if (pos >= T) return;
        const int len = lens[b];
        if ((int)blockIdx.x == scatter_chunks && t == 0)
            len_out[b] = (float)len;
        if (pos + 4 <= len) return;                 // covered by scatter
        float* row = beat + (size_t)b * T + pos;
        if (pos >= len) {
            *(float4*)row = make_float4(0.f, 0.f, 0.f, 0.f);
        } else {
            #pragma unroll
            for (int k = 0; k < 4; ++k)
                if (pos + k >= len) row[k] = 0.f;
        }
    }
}

extern "C" void kernel_launch(void* const* d_in, const int* in_sizes, int n_in,
                              void* d_out, int out_size, void* d_ws, size_t ws_size,
                              hipStream_t stream) {
    // inputs (setup_inputs order):
    // 0 syllable (B,S,D) f32 — UNUSED by reference
    // 1 syllable_num (B,S) i32
    // 2 syllable_lengths (B,) i32
    // 3 beat_syb (B,S) f32
    // 4 ds_alf (B,S,P) f32
    // 5 label_xml (B,T) i32 — zeros, unused
    // 6 label_xml_lengths (B,) i32
    const int*   syllable_num     = (const int*)  d_in[1];
    const int*   syllable_lengths = (const int*)  d_in[2];
    const float* beat_syb         = (const float*)d_in[3];
    const float* ds_alf           = (const float*)d_in[4];
    const int*   label_lengths    = (const int*)  d_in[6];

    const int B = in_sizes[2];
    const int S = in_sizes[1] / B;
    const int T = in_sizes[5] / B;

    float* beat = (float*)d_out;

    const int scatter_chunks = (S + 255) / 256;          // 32
    const int tail_chunks    = ((T >> 2) + 255) / 256;   // 128
    dim3 grid(scatter_chunks + tail_chunks, B);
    plr_fused<<<grid, 256, 0, stream>>>(
        syllable_num, syllable_lengths, beat_syb, ds_alf,
        label_lengths, beat, beat + (size_t)B * T, S, T, scatter_chunks);
}